// Round 6
// baseline (372.203 us; speedup 1.0000x reference)
//
#include <hip/hip_runtime.h>
#include <stdint.h>

#define TT 300
#define DD 40
#define SB 8                      // samples per block; grid 256
#define AROWH 192                 // halfwords per A row (16B-aligned rows; banks fixed by XOR swizzle)
#define ABYTES (16 * AROWH * 2)   // 6144 bytes per A buffer
#define WROW 224                  // staging stride in halfwords (448 B rows, 16B aligned)

typedef __attribute__((ext_vector_type(8))) short short8;
typedef __attribute__((ext_vector_type(4))) float f32x4;

__device__ __forceinline__ ushort f2bf(float f) {
  uint32_t b = __float_as_uint(f);
  b += 0x7FFFu + ((b >> 16) & 1u);   // RNE
  return (ushort)(b >> 16);
}

// Barrier that does NOT drain vmcnt: LDS ops retired (lgkmcnt), global loads stay in flight.
__device__ __forceinline__ void bar() {
  asm volatile("s_waitcnt lgkmcnt(0)" ::: "memory");
  __builtin_amdgcn_s_barrier();
  asm volatile("" ::: "memory");
}

// Swizzled byte offset into the A tile: row-major [16][AROWH] bf16 with
// byte ^= (row&7)<<4. Rows are 384 B (≡0 mod 128) so the XOR stays inside the
// row and preserves 16B alignment; A-frag ds_read_b128 is ≤2-way (free).
__device__ __forceinline__ int aswz(int row, int colh) {
  return ((row * AROWH + colh) * 2) ^ ((row & 7) << 4);
}

// K layout (192 = 6 ktiles of 32):
//   k  0..39  : x_t
//   k 40,41   : 1.0 (bf16) -> bias hi/lo folded into the matmul
//   k 42..63  : zero
//   k 64..191 : h interleaved: 64+2u = h_hi(u), 65+2u = h_lo(u); both use W row 40+u
// 8 waves, wave wv owns units 8wv..8wv+7 as 2 ntiles of 16 cols:
//   ntile nt, frag col nb -> gate g = nt + 2*(nb>>3), unit u = 8wv + (nb&7)
//   => lane (q=lane>>4, n=lane&15, m=n&7, b=n>>3) gets gates (b?f:i) in z0 and
//      (b?o:j) in z1 for unit 8wv+m; the other two gates come from lane n^8
//      via 4 __shfl_xor. Each lane handles ONE (sample,unit): sample 2q+b, unit 8wv+m.
// Sample row remap: sample s lives in A row 4*(s>>1)+(s&1)  (rows {0,1,4,5,8,9,12,13}).
// Rows with (row&3)>=2 are PERMANENT ZEROS -> lanes with (n&3)>=2 never read A from
// LDS (their frags are zero-initialized once); halves LDS read traffic per CU-step.
__global__ __launch_bounds__(512, 2) void lstm_mfma_kernel(
    const float* __restrict__ X, const int* __restrict__ seqlen,
    const float* __restrict__ Wk, const float* __restrict__ bias,
    float* __restrict__ hfin)
{
  __shared__ ushort shmem[64 * WROW];   // 28 KB; first 12288 B reused as A double-buffer
  char* const Ab = reinterpret_cast<char*>(shmem);

  const int tid = threadIdx.x;
  const int wv = tid >> 6, lane = tid & 63;
  const int q = lane >> 4, n = lane & 15, m = n & 7, b = n >> 3;
  const int s0 = blockIdx.x * SB;

  // ---- stage B fragments into registers (12 frags = 48 VGPRs/wave) ----
  // B[k][nb] fragment layout: nb = lane&15, k = ktile*32 + (lane>>4)*8 + j
  short8 Bf[6][2];
  for (int c = 0; c < 4; ++c) {          // round c stages cols for waves 2c, 2c+1
    for (int i = tid; i < 64 * 192; i += 512) {
      int cc = i & 63, kp = i >> 6;
      int nb = cc & 15, nt = (cc >> 4) & 1, ws = cc >> 5;
      int g = nt + 2 * (nb >> 3);
      int uu = (2 * c + ws) * 8 + (nb & 7);
      int col = g * 64 + uu;
      ushort v = 0;
      if (kp < 40) {
        v = f2bf(Wk[kp * 256 + col]);
      } else if (kp < 42) {              // bias as ones-row weights, hi + lo residual
        float bv = bias[col] + ((g == 2) ? 1.0f : 0.0f);   // forget-gate +1
        ushort hi = f2bf(bv);
        v = (kp == 40) ? hi : f2bf(bv - __uint_as_float((uint32_t)hi << 16));
      } else if (kp >= 64) {
        v = f2bf(Wk[(40 + ((kp - 64) >> 1)) * 256 + col]); // hi and lo share the weight row
      }
      shmem[cc * WROW + kp] = v;
    }
    __syncthreads();
    if ((wv >> 1) == c) {
      const int cbase = (wv & 1) * 32;
      #pragma unroll
      for (int kt = 0; kt < 6; ++kt) {
        #pragma unroll
        for (int nt = 0; nt < 2; ++nt)
          Bf[kt][nt] = *reinterpret_cast<const short8*>(
              &shmem[(cbase + nt * 16 + n) * WROW + kt * 32 + q * 8]);
      }
    }
    __syncthreads();                     // protect frag reads from next round's fill
  }

  // ---- reuse shmem[0..12288B) as the A double-buffer; zero it ----
  for (int i = tid; i < 6144; i += 512) shmem[i] = 0;
  __syncthreads();                       // zeros visible before ones/x0 writes (cross-wave)

  // ---- per-lane ownership: ONE (sample, unit) pair ----
  const int u = wv * 8 + m;
  const int sl = 2 * q + b;
  const int len = seqlen[s0 + sl];
  int ml = seqlen[s0 + (lane & 7)];      // block-max seqlen
  #pragma unroll
  for (int off = 1; off < 8; off <<= 1) ml = max(ml, __shfl_xor(ml, off));

  // x prefetch: 320 values/step; threads 0..319 own one (sample, dim) slot
  const bool hasX = (tid < SB * DD);
  const int sA = (tid * 205) >> 13, dA = tid - sA * 40;   // exact for tid<320
  const int rA = 4 * (sA >> 1) + (sA & 1);
  const float* pA = X + (size_t)(s0 + sA) * (TT * DD) + dA;
  const int xb = aswz(rA, dA);

  if (tid < 16) {   // ones at k=40,41 for the 8 real rows, BOTH buffers
    int s = tid & 7, bb = tid >> 3;
    int row = 4 * (s >> 1) + (s & 1);
    *reinterpret_cast<uint32_t*>(Ab + bb * ABYTES + aswz(row, 40)) = 0x3F803F80u;
  }
  float xv = 0.f;                        // x(t+1), consumed at step t
  if (hasX) {
    *reinterpret_cast<ushort*>(Ab + xb) = f2bf(pA[0]);    // x_0 into buffer 0
    if (ml > 1) xv = pA[DD];
  }
  __syncthreads();
  pA += 2 * DD;                          // points at x(t+2) for t=0

  // A-frag swizzled byte offsets (loop-invariant, constant-indexed -> registers)
  int aoff[6];
  #pragma unroll
  for (int kt = 0; kt < 6; ++kt)
    aoff[kt] = (n * 384 + kt * 64 + q * 16) ^ (m << 4);

  // Lanes whose A-row is structurally zero never read A: frags stay zero forever.
  const bool readA = ((n & 3) < 2);
  const short8 z8 = {0, 0, 0, 0, 0, 0, 0, 0};
  short8 aAx0 = z8, aAx1 = z8, aAh0 = z8, aAh1 = z8, aAh2 = z8, aAh3 = z8;

  float cst = 0.f, hf = 0.f;
  int rb = 0, wb = ABYTES;
  const int hb = aswz(4 * q + b, 64 + 2 * u);   // my sample's h slot (4B aligned)

  for (int t = 0; t < ml; ++t) {
    // --- A-frag reads: only the 32 real-row lanes touch LDS (exec-masked) ---
    if (readA) {
      aAx0 = *reinterpret_cast<const short8*>(Ab + rb + aoff[0]);
      aAx1 = *reinterpret_cast<const short8*>(Ab + rb + aoff[1]);
      aAh0 = *reinterpret_cast<const short8*>(Ab + rb + aoff[2]);
      aAh1 = *reinterpret_cast<const short8*>(Ab + rb + aoff[3]);
      aAh2 = *reinterpret_cast<const short8*>(Ab + rb + aoff[4]);
      aAh3 = *reinterpret_cast<const short8*>(Ab + rb + aoff[5]);
    }

    f32x4 zero4 = {0.f, 0.f, 0.f, 0.f};
    // x-MFMAs first: their frags were ready at the barrier; fill the h ds_read shadow
    f32x4 ac00 = __builtin_amdgcn_mfma_f32_16x16x32_bf16(aAx0, Bf[0][0], zero4, 0, 0, 0);
    f32x4 ac01 = __builtin_amdgcn_mfma_f32_16x16x32_bf16(aAx0, Bf[0][1], zero4, 0, 0, 0);
    ac00 = __builtin_amdgcn_mfma_f32_16x16x32_bf16(aAx1, Bf[1][0], ac00, 0, 0, 0);
    ac01 = __builtin_amdgcn_mfma_f32_16x16x32_bf16(aAx1, Bf[1][1], ac01, 0, 0, 0);

    // publish x(t+1) (loaded last iteration) into the NEXT buffer; issue x(t+2) load
    if (hasX && t + 1 < ml) *reinterpret_cast<ushort*>(Ab + wb + xb) = f2bf(xv);
    float xn = 0.f;
    if (hasX && t + 2 < ml) { xn = pA[0]; pA += DD; }

    // h part: independent accumulators (chain = last read + one MFMA + 2 adds)
    f32x4 ac10 = __builtin_amdgcn_mfma_f32_16x16x32_bf16(aAh0, Bf[2][0], zero4, 0, 0, 0);
    f32x4 ac11 = __builtin_amdgcn_mfma_f32_16x16x32_bf16(aAh0, Bf[2][1], zero4, 0, 0, 0);
    f32x4 ac20 = __builtin_amdgcn_mfma_f32_16x16x32_bf16(aAh1, Bf[3][0], zero4, 0, 0, 0);
    f32x4 ac21 = __builtin_amdgcn_mfma_f32_16x16x32_bf16(aAh1, Bf[3][1], zero4, 0, 0, 0);
    f32x4 ac30 = __builtin_amdgcn_mfma_f32_16x16x32_bf16(aAh2, Bf[4][0], zero4, 0, 0, 0);
    f32x4 ac31 = __builtin_amdgcn_mfma_f32_16x16x32_bf16(aAh2, Bf[4][1], zero4, 0, 0, 0);
    ac00 = __builtin_amdgcn_mfma_f32_16x16x32_bf16(aAh3, Bf[5][0], ac00, 0, 0, 0);
    ac01 = __builtin_amdgcn_mfma_f32_16x16x32_bf16(aAh3, Bf[5][1], ac01, 0, 0, 0);

    // only accumulator components 0,1 are used (rows 4q+0, 4q+1 = real samples)
    float z00 = (ac00[0] + ac10[0]) + (ac20[0] + ac30[0]);
    float z01 = (ac00[1] + ac10[1]) + (ac20[1] + ac30[1]);
    float z10 = (ac01[0] + ac11[0]) + (ac21[0] + ac31[0]);
    float z11 = (ac01[1] + ac11[1]) + (ac21[1] + ac31[1]);

    // gather the 4 gates of MY (sample,unit): partner lane n^8 holds the other pair
    float p00 = __shfl_xor(z00, 8);
    float p01 = __shfl_xor(z01, 8);
    float p10 = __shfl_xor(z10, 8);
    float p11 = __shfl_xor(z11, 8);
    float gi = b ? p01 : z00;
    float gf = b ? z01 : p00;
    float gj = b ? p11 : z10;
    float go = b ? z11 : p10;

    // sigm(i)*tanh(j) = (Ej-1)*rcp((1+Ei)(1+Ej)); tanh(nc)*sigm(o) likewise. Bias already in.
    float Ef = __expf(-gf), Ei = __expf(-gi), Ej = __expf(2.f * gj);
    float nc = fmaf(cst, __builtin_amdgcn_rcpf(1.f + Ef),
                    (Ej - 1.f) * __builtin_amdgcn_rcpf((1.f + Ei) * (1.f + Ej)));
    float En = __expf(2.f * fminf(nc, 44.f)), Eo = __expf(-go);
    float nh = (En - 1.f) * __builtin_amdgcn_rcpf((1.f + En) * (1.f + Eo));
    cst = nc;
    if (t == len - 1) hf = nh;

    // h feedback: truncated hi + truncated lo residual (total err ~2^-18), one b32 write
    ushort hh = (ushort)(__float_as_uint(nh) >> 16);
    float rem = nh - __uint_as_float((uint32_t)hh << 16);
    ushort hl = (ushort)(__float_as_uint(rem) >> 16);
    *reinterpret_cast<uint32_t*>(Ab + wb + hb) = (uint32_t)hh | ((uint32_t)hl << 16);

    bar();   // single barrier/step: publishes buf[t+1], retires reads of buf[t]; vmcnt untouched
    rb ^= ABYTES; wb ^= ABYTES;
    xv = xn;
  }

  hfin[(size_t)(s0 + sl) * 64 + u] = hf;
}

// head: 16 samples per block (128 blocks) -> W2 read 128x instead of 2048x
__global__ __launch_bounds__(256, 1) void head_kernel(
    const float* __restrict__ hfin,
    const float* __restrict__ W1, const float* __restrict__ b1,
    const float* __restrict__ gamma, const float* __restrict__ beta,
    const float* __restrict__ mmean, const float* __restrict__ mvar,
    const float* __restrict__ W2, const float* __restrict__ b2,
    float* __restrict__ out)
{
  __shared__ float hl[16 * 64];     // 4 KB
  __shared__ float d1t[128 * 20];   // transposed d1 [k][s], stride 20 (16B-aligned)
  __shared__ float lg[16 * 516];    // 33 KB logits
  const int tid = threadIdx.x;
  const int b0 = blockIdx.x * 16;

  for (int i = tid; i < 16 * 64; i += 256) hl[i] = hfin[(size_t)b0 * 64 + i];
  __syncthreads();

  { // dense1 + BN + ReLU: thread = (col j, sample-group sg), 8 samples each
    const int j = tid & 127, sg = tid >> 7;
    float acc[8];
    const float bb = b1[j];
    #pragma unroll
    for (int s = 0; s < 8; ++s) acc[s] = bb;
    for (int k = 0; k < 64; ++k) {
      float w = W1[k * 128 + j];
      #pragma unroll
      for (int s = 0; s < 8; ++s) acc[s] = fmaf(hl[(sg * 8 + s) * 64 + k], w, acc[s]);
    }
    const float ga = gamma[j], be = beta[j], mm = mmean[j];
    const float iv = rsqrtf(mvar[j] + 1e-3f);
    #pragma unroll
    for (int s = 0; s < 8; ++s) {
      float v = fmaxf(acc[s], 0.f);
      d1t[j * 20 + sg * 8 + s] = ga * (v - mm) * iv + be;
    }
  }
  __syncthreads();

  { // logits: thread owns cols 2*tid, 2*tid+1 for all 16 samples
    const int cA = tid * 2;
    float accA[16], accB[16];
    const float bA = b2[cA], bB = b2[cA + 1];
    #pragma unroll
    for (int s = 0; s < 16; ++s) { accA[s] = bA; accB[s] = bB; }
    for (int k = 0; k < 128; ++k) {
      const float2 w = *reinterpret_cast<const float2*>(&W2[k * 512 + cA]);
      const f32x4 dq0 = *reinterpret_cast<const f32x4*>(&d1t[k * 20]);
      const f32x4 dq1 = *reinterpret_cast<const f32x4*>(&d1t[k * 20 + 4]);
      const f32x4 dq2 = *reinterpret_cast<const f32x4*>(&d1t[k * 20 + 8]);
      const f32x4 dq3 = *reinterpret_cast<const f32x4*>(&d1t[k * 20 + 12]);
      #pragma unroll
      for (int s = 0; s < 4; ++s) {
        accA[s]      = fmaf(dq0[s], w.x, accA[s]);      accB[s]      = fmaf(dq0[s], w.y, accB[s]);
        accA[s + 4]  = fmaf(dq1[s], w.x, accA[s + 4]);  accB[s + 4]  = fmaf(dq1[s], w.y, accB[s + 4]);
        accA[s + 8]  = fmaf(dq2[s], w.x, accA[s + 8]);  accB[s + 8]  = fmaf(dq2[s], w.y, accB[s + 8]);
        accA[s + 12] = fmaf(dq3[s], w.x, accA[s + 12]); accB[s + 12] = fmaf(dq3[s], w.y, accB[s + 12]);
      }
    }
    #pragma unroll
    for (int s = 0; s < 16; ++s) {
      lg[s * 516 + cA]     = accA[s];
      lg[s * 516 + cA + 1] = accB[s];
    }
  }
  __syncthreads();

  { // softmax: wave handles 4 samples, 8 cols/lane
    const int w = tid >> 6, lane = tid & 63;
    #pragma unroll
    for (int si = 0; si < 4; ++si) {
      const int s = w * 4 + si;
      float v[8];
      float mx = -3.4e38f;
      #pragma unroll
      for (int i = 0; i < 8; ++i) { v[i] = lg[s * 516 + lane + 64 * i]; mx = fmaxf(mx, v[i]); }
      #pragma unroll
      for (int off = 1; off < 64; off <<= 1) mx = fmaxf(mx, __shfl_xor(mx, off));
      float sum = 0.f;
      #pragma unroll
      for (int i = 0; i < 8; ++i) { v[i] = __expf(v[i] - mx); sum += v[i]; }
      #pragma unroll
      for (int off = 1; off < 64; off <<= 1) sum += __shfl_xor(sum, off);
      const float inv = __builtin_amdgcn_rcpf(sum);
      #pragma unroll
      for (int i = 0; i < 8; ++i)
        out[(size_t)(b0 + s) * 512 + lane + 64 * i] = v[i] * inv;
    }
  }
}

extern "C" void kernel_launch(void* const* d_in, const int* in_sizes, int n_in,
                              void* d_out, int out_size, void* d_ws, size_t ws_size,
                              hipStream_t stream) {
  const float* X      = (const float*)d_in[0];
  const int*   seqlen = (const int*)d_in[1];
  const float* Wk     = (const float*)d_in[2];
  const float* bias   = (const float*)d_in[3];
  const float* W1     = (const float*)d_in[4];
  const float* b1     = (const float*)d_in[5];
  const float* gam    = (const float*)d_in[6];
  const float* bet    = (const float*)d_in[7];
  const float* mmean  = (const float*)d_in[8];
  const float* mvar   = (const float*)d_in[9];
  const float* W2     = (const float*)d_in[10];
  const float* b2     = (const float*)d_in[11];
  float* out  = (float*)d_out;
  float* hfin = (float*)d_ws;   // 2048*64 fp32 = 512 KB

  lstm_mfma_kernel<<<dim3(2048 / SB), dim3(512), 0, stream>>>(X, seqlen, Wk, bias, hfin);
  head_kernel<<<dim3(128), dim3(256), 0, stream>>>(hfin, W1, b1, gam, bet,
                                                   mmean, mvar, W2, b2, out);
}

// Round 7
// 350.721 us; speedup vs baseline: 1.0613x; 1.0613x over previous
//
#include <hip/hip_runtime.h>
#include <stdint.h>

#define TT 300
#define DD 40
#define SB 8                     // samples per block; grid 256
#define ABYTES (8 * 192 * 2)     // 3072 B per A buffer (8 rows x 192 bf16)
#define WROW 224                 // staging stride in halfwords (448 B rows, 16B aligned)

typedef __attribute__((ext_vector_type(8))) short short8;
typedef __attribute__((ext_vector_type(4))) float f32x4;

__device__ __forceinline__ ushort f2bf(float f) {
  uint32_t b = __float_as_uint(f);
  b += 0x7FFFu + ((b >> 16) & 1u);   // RNE
  return (ushort)(b >> 16);
}

// Barrier that does NOT drain vmcnt: LDS ops retired (lgkmcnt), global loads stay in flight.
__device__ __forceinline__ void bar() {
  asm volatile("s_waitcnt lgkmcnt(0)" ::: "memory");
  __builtin_amdgcn_s_barrier();
  asm volatile("" ::: "memory");
}

// Swizzled byte offset into the 8-row A tile: row-major [8][192] bf16 with
// byte ^= row<<4. Rows are 384 B (≡0 mod 128) so the XOR stays inside the row
// and preserves 16B alignment; per 16-lane phase all 8 row-addresses hit
// distinct bank groups -> conflict-free.
__device__ __forceinline__ int aswz(int row, int colh) {
  return ((row * 192 + colh) * 2) ^ (row << 4);
}

// K layout (192 = 6 ktiles of 32):
//   k  0..39  : x_t        k 40,41 : 1.0 (bias hi/lo folded into matmul)
//   k 42..63  : zero       k 64..191 : h interleaved (64+2u = hi, 65+2u = lo; share W row 40+u)
// A tile has only 8 ROWS (row = sample). MFMA lanes 8..15 re-read row n&7
// (same-address broadcast); output rows 8..15 duplicate rows 0..7 and are
// consumed as such: lane (q,n) acc component r holds sample (q&1)*4 + r.
// Lane ownership: sample s = (q&1)*4 + (q>>1)*2 + b, unit u = 8*wv + (n&7).
// Gates: ntile nt at lane b = gate nt + 2b -> 2-shfl exchange with lane n^8.
__global__ __launch_bounds__(512, 2) void lstm_mfma_kernel(
    const float* __restrict__ X, const int* __restrict__ seqlen,
    const float* __restrict__ Wk, const float* __restrict__ bias,
    float* __restrict__ hfin)
{
  __shared__ ushort shmem[64 * WROW];   // 28 KB; first 6144 B reused as A double-buffer
  char* const Ab = reinterpret_cast<char*>(shmem);

  const int tid = threadIdx.x;
  const int wv = tid >> 6, lane = tid & 63;
  const int q = lane >> 4, n = lane & 15, m = n & 7, b = n >> 3;
  const int s0 = blockIdx.x * SB;

  // ---- stage B fragments into registers (12 frags = 48 VGPRs/wave) ----
  short8 Bf[6][2];
  for (int c = 0; c < 4; ++c) {          // round c stages cols for waves 2c, 2c+1
    for (int i = tid; i < 64 * 192; i += 512) {
      int cc = i & 63, kp = i >> 6;
      int nb = cc & 15, nt = (cc >> 4) & 1, ws = cc >> 5;
      int g = nt + 2 * (nb >> 3);
      int uu = (2 * c + ws) * 8 + (nb & 7);
      int col = g * 64 + uu;
      ushort v = 0;
      if (kp < 40) {
        v = f2bf(Wk[kp * 256 + col]);
      } else if (kp < 42) {              // bias as ones-row weights, hi + lo residual
        float bv = bias[col] + ((g == 2) ? 1.0f : 0.0f);   // forget-gate +1
        ushort hi = f2bf(bv);
        v = (kp == 40) ? hi : f2bf(bv - __uint_as_float((uint32_t)hi << 16));
      } else if (kp >= 64) {
        v = f2bf(Wk[(40 + ((kp - 64) >> 1)) * 256 + col]); // hi and lo share the weight row
      }
      shmem[cc * WROW + kp] = v;
    }
    __syncthreads();
    if ((wv >> 1) == c) {
      const int cbase = (wv & 1) * 32;
      #pragma unroll
      for (int kt = 0; kt < 6; ++kt) {
        #pragma unroll
        for (int nt = 0; nt < 2; ++nt)
          Bf[kt][nt] = *reinterpret_cast<const short8*>(
              &shmem[(cbase + nt * 16 + n) * WROW + kt * 32 + q * 8]);
      }
    }
    __syncthreads();                     // protect frag reads from next round's fill
  }

  // ---- reuse shmem[0..6144B) as the A double-buffer; zero it ----
  for (int i = tid; i < 3072; i += 512) shmem[i] = 0;
  __syncthreads();                       // zeros visible before ones/x0 writes (cross-wave)

  // ---- per-lane ownership: ONE (sample, unit) pair ----
  const int hi2 = q >> 1;
  const int u = wv * 8 + m;
  const int sl = (q & 1) * 4 + hi2 * 2 + b;
  const int len = seqlen[s0 + sl];
  int ml = seqlen[s0 + (lane & 7)];      // block-max seqlen
  #pragma unroll
  for (int off = 1; off < 8; off <<= 1) ml = max(ml, __shfl_xor(ml, off));

  // x prefetch: 320 values/step; threads 0..319 own one (sample, dim) slot; row = sample
  const bool hasX = (tid < SB * DD);
  const int sA = (tid * 205) >> 13, dA = tid - sA * 40;   // exact for tid<320
  const float* pA = X + (size_t)(s0 + sA) * (TT * DD) + dA;
  const int xb = aswz(sA, dA);

  if (tid < 16) {   // ones at k=40,41 for all 8 rows, BOTH buffers
    int s = tid & 7, bb = tid >> 3;
    *reinterpret_cast<uint32_t*>(Ab + bb * ABYTES + aswz(s, 40)) = 0x3F803F80u;
  }
  float xv = 0.f;                        // x(t+1), consumed at step t
  if (hasX) {
    *reinterpret_cast<ushort*>(Ab + xb) = f2bf(pA[0]);    // x_0 into buffer 0
    if (ml > 1) xv = pA[DD];
  }
  __syncthreads();
  pA += 2 * DD;                          // points at x(t+2) for t=0

  // A-frag swizzled byte offsets (loop-invariant): row = n&7 (lanes 8..15 duplicate)
  int aoff[6];
  #pragma unroll
  for (int kt = 0; kt < 6; ++kt)
    aoff[kt] = (m * 384 + kt * 64 + q * 16) ^ (m << 4);

  float cst = 0.f, hf = 0.f;
  float xvl = xv;
  const int hb = aswz(sl, 64 + 2 * u);   // my (sample,unit) h slot (4B aligned)
  const f32x4 zero4 = {0.f, 0.f, 0.f, 0.f};

  auto STEP = [&](int t, int RB, int WB) {
    // A-frag reads (2-way broadcast pairs, conflict-free)
    short8 Ax0 = *reinterpret_cast<const short8*>(Ab + RB + aoff[0]);
    short8 Ax1 = *reinterpret_cast<const short8*>(Ab + RB + aoff[1]);
    short8 Ah0 = *reinterpret_cast<const short8*>(Ab + RB + aoff[2]);
    short8 Ah1 = *reinterpret_cast<const short8*>(Ab + RB + aoff[3]);
    short8 Ah2 = *reinterpret_cast<const short8*>(Ab + RB + aoff[4]);
    short8 Ah3 = *reinterpret_cast<const short8*>(Ab + RB + aoff[5]);

    // x-MFMAs first (frags ready since barrier); single chained acc per ntile
    f32x4 ac0 = __builtin_amdgcn_mfma_f32_16x16x32_bf16(Ax0, Bf[0][0], zero4, 0, 0, 0);
    f32x4 ac1 = __builtin_amdgcn_mfma_f32_16x16x32_bf16(Ax0, Bf[0][1], zero4, 0, 0, 0);
    ac0 = __builtin_amdgcn_mfma_f32_16x16x32_bf16(Ax1, Bf[1][0], ac0, 0, 0, 0);
    ac1 = __builtin_amdgcn_mfma_f32_16x16x32_bf16(Ax1, Bf[1][1], ac1, 0, 0, 0);

    // publish x(t+1) (loaded last iteration) into the NEXT buffer; issue x(t+2) load
    if (hasX && t + 1 < ml) *reinterpret_cast<ushort*>(Ab + WB + xb) = f2bf(xvl);
    float xn = 0.f;
    if (hasX && t + 2 < ml) { xn = pA[0]; pA += DD; }

    ac0 = __builtin_amdgcn_mfma_f32_16x16x32_bf16(Ah0, Bf[2][0], ac0, 0, 0, 0);
    ac1 = __builtin_amdgcn_mfma_f32_16x16x32_bf16(Ah0, Bf[2][1], ac1, 0, 0, 0);
    ac0 = __builtin_amdgcn_mfma_f32_16x16x32_bf16(Ah1, Bf[3][0], ac0, 0, 0, 0);
    ac1 = __builtin_amdgcn_mfma_f32_16x16x32_bf16(Ah1, Bf[3][1], ac1, 0, 0, 0);
    ac0 = __builtin_amdgcn_mfma_f32_16x16x32_bf16(Ah2, Bf[4][0], ac0, 0, 0, 0);
    ac1 = __builtin_amdgcn_mfma_f32_16x16x32_bf16(Ah2, Bf[4][1], ac1, 0, 0, 0);
    ac0 = __builtin_amdgcn_mfma_f32_16x16x32_bf16(Ah3, Bf[5][0], ac0, 0, 0, 0);
    ac1 = __builtin_amdgcn_mfma_f32_16x16x32_bf16(Ah3, Bf[5][1], ac1, 0, 0, 0);

    // select my 2 components (samples base, base+1), exchange 2 values with lane n^8
    float v0_s0 = hi2 ? ac0[2] : ac0[0];
    float v0_s1 = hi2 ? ac0[3] : ac0[1];
    float v1_s0 = hi2 ? ac1[2] : ac1[0];
    float v1_s1 = hi2 ? ac1[3] : ac1[1];
    float own0 = b ? v0_s1 : v0_s0;      // gate 2b   of my sample
    float own1 = b ? v1_s1 : v1_s0;      // gate 2b+1 of my sample
    float snd0 = b ? v0_s0 : v0_s1;      // gate 2b   of partner's sample
    float snd1 = b ? v1_s0 : v1_s1;
    float rcv0 = __shfl_xor(snd0, 8);    // gate 2(1-b) of my sample
    float rcv1 = __shfl_xor(snd1, 8);
    float gi = b ? rcv0 : own0;
    float gj = b ? rcv1 : own1;
    float gf = b ? own0 : rcv0;
    float go = b ? own1 : rcv1;

    // sigm(i)*tanh(j) = (Ej-1)*rcp((1+Ei)(1+Ej)); tanh(nc)*sigm(o) likewise. Bias already in.
    float Ef = __expf(-gf), Ei = __expf(-gi), Ej = __expf(2.f * gj);
    float nc = fmaf(cst, __builtin_amdgcn_rcpf(1.f + Ef),
                    (Ej - 1.f) * __builtin_amdgcn_rcpf((1.f + Ei) * (1.f + Ej)));
    float En = __expf(2.f * fminf(nc, 44.f)), Eo = __expf(-go);
    float nh = (En - 1.f) * __builtin_amdgcn_rcpf((1.f + En) * (1.f + Eo));
    cst = nc;
    if (t == len - 1) hf = nh;

    // h feedback: truncated hi + truncated lo residual (err ~2^-18), one b32 write
    ushort hh = (ushort)(__float_as_uint(nh) >> 16);
    float rem = nh - __uint_as_float((uint32_t)hh << 16);
    ushort hl = (ushort)(__float_as_uint(rem) >> 16);
    *reinterpret_cast<uint32_t*>(Ab + WB + hb) = (uint32_t)hh | ((uint32_t)hl << 16);

    bar();   // single barrier/step: publishes buf[t+1], retires reads of buf[t]
    xvl = xn;
  };

  for (int t = 0; t < ml; ) {            // ml is block-uniform -> uniform branches
    STEP(t, 0, ABYTES); ++t;
    if (t >= ml) break;
    STEP(t, ABYTES, 0); ++t;
  }

  hfin[(size_t)(s0 + sl) * 64 + u] = hf;
}

// head: 16 samples per block (128 blocks) -> W2 read 128x instead of 2048x
__global__ __launch_bounds__(256, 1) void head_kernel(
    const float* __restrict__ hfin,
    const float* __restrict__ W1, const float* __restrict__ b1,
    const float* __restrict__ gamma, const float* __restrict__ beta,
    const float* __restrict__ mmean, const float* __restrict__ mvar,
    const float* __restrict__ W2, const float* __restrict__ b2,
    float* __restrict__ out)
{
  __shared__ float hl[16 * 64];     // 4 KB
  __shared__ float d1t[128 * 20];   // transposed d1 [k][s], stride 20 (16B-aligned)
  __shared__ float lg[16 * 516];    // 33 KB logits
  const int tid = threadIdx.x;
  const int b0 = blockIdx.x * 16;

  for (int i = tid; i < 16 * 64; i += 256) hl[i] = hfin[(size_t)b0 * 64 + i];
  __syncthreads();

  { // dense1 + BN + ReLU: thread = (col j, sample-group sg), 8 samples each
    const int j = tid & 127, sg = tid >> 7;
    float acc[8];
    const float bb = b1[j];
    #pragma unroll
    for (int s = 0; s < 8; ++s) acc[s] = bb;
    for (int k = 0; k < 64; ++k) {
      float w = W1[k * 128 + j];
      #pragma unroll
      for (int s = 0; s < 8; ++s) acc[s] = fmaf(hl[(sg * 8 + s) * 64 + k], w, acc[s]);
    }
    const float ga = gamma[j], be = beta[j], mm = mmean[j];
    const float iv = rsqrtf(mvar[j] + 1e-3f);
    #pragma unroll
    for (int s = 0; s < 8; ++s) {
      float v = fmaxf(acc[s], 0.f);
      d1t[j * 20 + sg * 8 + s] = ga * (v - mm) * iv + be;
    }
  }
  __syncthreads();

  { // logits: thread owns cols 2*tid, 2*tid+1 for all 16 samples
    const int cA = tid * 2;
    float accA[16], accB[16];
    const float bA = b2[cA], bB = b2[cA + 1];
    #pragma unroll
    for (int s = 0; s < 16; ++s) { accA[s] = bA; accB[s] = bB; }
    for (int k = 0; k < 128; ++k) {
      const float2 w = *reinterpret_cast<const float2*>(&W2[k * 512 + cA]);
      const f32x4 dq0 = *reinterpret_cast<const f32x4*>(&d1t[k * 20]);
      const f32x4 dq1 = *reinterpret_cast<const f32x4*>(&d1t[k * 20 + 4]);
      const f32x4 dq2 = *reinterpret_cast<const f32x4*>(&d1t[k * 20 + 8]);
      const f32x4 dq3 = *reinterpret_cast<const f32x4*>(&d1t[k * 20 + 12]);
      #pragma unroll
      for (int s = 0; s < 4; ++s) {
        accA[s]      = fmaf(dq0[s], w.x, accA[s]);      accB[s]      = fmaf(dq0[s], w.y, accB[s]);
        accA[s + 4]  = fmaf(dq1[s], w.x, accA[s + 4]);  accB[s + 4]  = fmaf(dq1[s], w.y, accB[s + 4]);
        accA[s + 8]  = fmaf(dq2[s], w.x, accA[s + 8]);  accB[s + 8]  = fmaf(dq2[s], w.y, accB[s + 8]);
        accA[s + 12] = fmaf(dq3[s], w.x, accA[s + 12]); accB[s + 12] = fmaf(dq3[s], w.y, accB[s + 12]);
      }
    }
    #pragma unroll
    for (int s = 0; s < 16; ++s) {
      lg[s * 516 + cA]     = accA[s];
      lg[s * 516 + cA + 1] = accB[s];
    }
  }
  __syncthreads();

  { // softmax: wave handles 4 samples, 8 cols/lane
    const int w = tid >> 6, lane = tid & 63;
    #pragma unroll
    for (int si = 0; si < 4; ++si) {
      const int s = w * 4 + si;
      float v[8];
      float mx = -3.4e38f;
      #pragma unroll
      for (int i = 0; i < 8; ++i) { v[i] = lg[s * 516 + lane + 64 * i]; mx = fmaxf(mx, v[i]); }
      #pragma unroll
      for (int off = 1; off < 64; off <<= 1) mx = fmaxf(mx, __shfl_xor(mx, off));
      float sum = 0.f;
      #pragma unroll
      for (int i = 0; i < 8; ++i) { v[i] = __expf(v[i] - mx); sum += v[i]; }
      #pragma unroll
      for (int off = 1; off < 64; off <<= 1) sum += __shfl_xor(sum, off);
      const float inv = __builtin_amdgcn_rcpf(sum);
      #pragma unroll
      for (int i = 0; i < 8; ++i)
        out[(size_t)(b0 + s) * 512 + lane + 64 * i] = v[i] * inv;
    }
  }
}

extern "C" void kernel_launch(void* const* d_in, const int* in_sizes, int n_in,
                              void* d_out, int out_size, void* d_ws, size_t ws_size,
                              hipStream_t stream) {
  const float* X      = (const float*)d_in[0];
  const int*   seqlen = (const int*)d_in[1];
  const float* Wk     = (const float*)d_in[2];
  const float* bias   = (const float*)d_in[3];
  const float* W1     = (const float*)d_in[4];
  const float* b1     = (const float*)d_in[5];
  const float* gam    = (const float*)d_in[6];
  const float* bet    = (const float*)d_in[7];
  const float* mmean  = (const float*)d_in[8];
  const float* mvar   = (const float*)d_in[9];
  const float* W2     = (const float*)d_in[10];
  const float* b2     = (const float*)d_in[11];
  float* out  = (float*)d_out;
  float* hfin = (float*)d_ws;   // 2048*64 fp32 = 512 KB

  lstm_mfma_kernel<<<dim3(2048 / SB), dim3(512), 0, stream>>>(X, seqlen, Wk, bias, hfin);
  head_kernel<<<dim3(128), dim3(256), 0, stream>>>(hfin, W1, b1, gam, bet,
                                                   mmean, mvar, W2, b2, out);
}